// Round 4
// baseline (46.500 us; speedup 1.0000x reference)
//
#include <hip/hip_runtime.h>
#include <stdint.h>

typedef __bf16 bf16;
typedef __bf16 bf16x8 __attribute__((ext_vector_type(8)));
typedef float f32x4 __attribute__((ext_vector_type(4)));

#define LQn   2048
#define LKVn  1024
#define DM    512
#define NH    8

static __device__ __forceinline__ f32x4 mfma_bf16(bf16x8 a, bf16x8 b, f32x4 c) {
  return __builtin_amdgcn_mfma_f32_16x16x32_bf16(a, b, c, 0, 0, 0);
}

// global -> LDS direct copy, 16 B per lane. ldsptr must be wave-uniform base.
static __device__ __forceinline__ void gl_lds16(const void* g, void* l) {
  __builtin_amdgcn_global_load_lds(
      (const __attribute__((address_space(1))) void*)g,
      (__attribute__((address_space(3))) void*)l, 16, 0, 0);
}

// Swizzle convention for all "tile-swizzled" global bf16 buffers (512 cols):
// within each 64-col group, logical unit u (8 bf16) of row R is stored at
// unit u ^ (R & 7).  Linear global_load_lds of a [rows][64-col] tile then
// yields LDS[r][u_phys] with u_phys = u ^ (R&7), matching the MFMA-side
// read formula  unit_phys = (ub + hi4) ^ (row & 7).

// ---------- weight transpose+convert (pre-swizzled): from W[k*512+n]
__global__ __launch_bounds__(256) void transpose_w_kernel(
    const float* __restrict__ Wq, const float* __restrict__ Wk,
    const float* __restrict__ Wv, const float* __restrict__ Wo,
    bf16* __restrict__ WTs) {
  __shared__ float tile[64 * 65];
  const int bid = blockIdx.x;
  const int mat = bid >> 6;
  const int tb  = bid & 63;
  const int r0 = (tb >> 3) * 64;  // k block
  const int c0 = (tb & 7) * 64;   // n block
  const float* W = (mat == 0) ? Wq : (mat == 1) ? Wk : (mat == 2) ? Wv : Wo;
  const int t = threadIdx.x;
#pragma unroll
  for (int i = 0; i < 16; ++i) {
    int idx = i * 256 + t;
    int r = idx >> 6, c = idx & 63;
    tile[r * 65 + c] = W[(size_t)(r0 + r) * DM + c0 + c];
  }
  __syncthreads();
#pragma unroll
  for (int i = 0; i < 16; ++i) {
    int idx = i * 256 + t;
    int r = idx >> 6, c = idx & 63;
    int n = c0 + r, k = r0 + c;    // logical WT[n][k]
    int ks = (k & ~63) | ((((k >> 3) & 7) ^ (n & 7)) << 3) | (k & 7);
    WTs[(size_t)mat * DM * DM + (size_t)n * DM + ks] = (bf16)tile[c * 65 + r];
  }
}

// ---------- projection tile 128x128, 512 threads (8 waves, 2M x 4N).
// B staged via global_load_lds (pre-swizzled WTs), double-buffered.
// A staged via regs (fp32 -> bf16 hi/lo), prefetched one k-step ahead.
template <bool SPLIT, bool SWZ_OUT>
__device__ __forceinline__ void proj_tile(const float* __restrict__ Ap,
                                          const bf16* __restrict__ Bs,
                                          bf16* __restrict__ Chi,
                                          bf16* __restrict__ Clo,
                                          int m0, int n0,
                                          bf16* smAh, bf16* smAl, bf16* smB) {
  const int t = threadIdx.x;
  const int lane = t & 63;
  const int w = t >> 6;            // 0..7
  const int ln = lane & 15, hi4 = lane >> 4;
  const int wr = w >> 2, wc = w & 3;
  const int rS = t >> 3, uS = t & 7;   // staging row/unit helpers
  const f32x4 zf = {0.f, 0.f, 0.f, 0.f};
  f32x4 acc[4][2];
#pragma unroll
  for (int a = 0; a < 4; ++a)
#pragma unroll
    for (int b = 0; b < 2; ++b) acc[a][b] = zf;

  bf16x8 ahv[2], alv[2], nahv[2], nalv[2];

  auto issueB = [&](int ko, int buf) {
#pragma unroll
    for (int i = 0; i < 2; ++i) {
      const bf16* src = Bs + (size_t)(n0 + i * 64 + rS) * 512 + ko + uS * 8;
      gl_lds16(src, smB + buf * 8192 + i * 4096 + w * 512);
    }
  };
  auto loadA = [&](int ko, bf16x8* hv8, bf16x8* lv8) {
#pragma unroll
    for (int i = 0; i < 2; ++i) {
      const float* g = Ap + (size_t)(m0 + i * 64 + rS) * 512 + ko + uS * 8;
      f32x4 x0 = *(const f32x4*)g, x1 = *(const f32x4*)(g + 4);
      bf16x8 hv, lv;
#pragma unroll
      for (int e = 0; e < 4; ++e) {
        float x = x0[e]; bf16 hh = (bf16)x; hv[e] = hh;
        float y = x1[e]; bf16 h2 = (bf16)y; hv[4 + e] = h2;
        if constexpr (SPLIT) { lv[e] = (bf16)(x - (float)hh); lv[4 + e] = (bf16)(y - (float)h2); }
      }
      hv8[i] = hv; lv8[i] = lv;
    }
  };
  auto writeA = [&](bf16x8* hv8, bf16x8* lv8) {
#pragma unroll
    for (int i = 0; i < 2; ++i) {
      int r = i * 64 + rS;
      int sw = r * 64 + ((uS ^ (r & 7)) * 8);
      *(bf16x8*)&smAh[sw] = hv8[i];
      if constexpr (SPLIT) *(bf16x8*)&smAl[sw] = lv8[i];
    }
  };

  issueB(0, 0);
  loadA(0, ahv, alv);
  writeA(ahv, alv);
  __syncthreads();

  int buf = 0;
  for (int kt = 0; kt < 8; ++kt) {
    if (kt < 7) {
      issueB((kt + 1) * 64, buf ^ 1);
      loadA((kt + 1) * 64, nahv, nalv);
    }
#pragma unroll
    for (int kk = 0; kk < 64; kk += 32) {
      const int ub = kk >> 3;
      bf16x8 ah[4], al[4], bh[2];
#pragma unroll
      for (int mf = 0; mf < 4; ++mf) {
        int addr = (wr * 64 + mf * 16 + ln) * 64 + (((ub + hi4) ^ (ln & 7)) * 8);
        ah[mf] = *(const bf16x8*)&smAh[addr];
        if constexpr (SPLIT) al[mf] = *(const bf16x8*)&smAl[addr];
      }
#pragma unroll
      for (int nf = 0; nf < 2; ++nf) {
        int addr = buf * 8192 + (wc * 32 + nf * 16 + ln) * 64 +
                   (((ub + hi4) ^ (ln & 7)) * 8);
        bh[nf] = *(const bf16x8*)&smB[addr];
      }
#pragma unroll
      for (int mf = 0; mf < 4; ++mf)
#pragma unroll
        for (int nf = 0; nf < 2; ++nf) {
          acc[mf][nf] = mfma_bf16(ah[mf], bh[nf], acc[mf][nf]);
          if constexpr (SPLIT) acc[mf][nf] = mfma_bf16(al[mf], bh[nf], acc[mf][nf]);
        }
    }
    if (kt < 7) {
      __syncthreads();               // drains: B(kt+1) in LDS, smA reads done
      writeA(nahv, nalv);
      __syncthreads();
      buf ^= 1;
    }
  }
#pragma unroll
  for (int mf = 0; mf < 4; ++mf)
#pragma unroll
    for (int nf = 0; nf < 2; ++nf)
#pragma unroll
      for (int e = 0; e < 4; ++e) {
        int row = m0 + wr * 64 + mf * 16 + hi4 * 4 + e;
        int col = n0 + wc * 32 + nf * 16 + ln;
        if constexpr (SWZ_OUT)
          col = (col & ~63) | ((((col >> 3) & 7) ^ (row & 7)) << 3) | (col & 7);
        size_t off = (size_t)row * 512 + col;
        float x = acc[mf][nf][e];
        bf16 h = (bf16)x;
        Chi[off] = h;
        if constexpr (SPLIT) Clo[off] = (bf16)(x - (float)h);
      }
}

// ---------- fused Q/K/V projection (Q,K split hi/lo swizzled; V plain bf16)
__global__ __launch_bounds__(512, 2) void proj_kernel(
    const float* __restrict__ q, const float* __restrict__ k,
    const float* __restrict__ v, const bf16* __restrict__ WTs,
    bf16* __restrict__ Qhi, bf16* __restrict__ Qlo,
    bf16* __restrict__ Khi, bf16* __restrict__ Klo, bf16* __restrict__ Vb) {
  __shared__ bf16 smAh[128 * 64];
  __shared__ bf16 smAl[128 * 64];
  __shared__ bf16 smB[2 * 128 * 64];
  const int bid = ((blockIdx.x & 7) << 5) | (blockIdx.x >> 3);  // XCD-chunked
  if (bid < 128) {            // Q: 32x4 tiles
    int m0 = (bid >> 2) * 128, n0 = (bid & 3) * 128;
    proj_tile<true, true>(q, WTs, Qhi, Qlo, m0, n0, smAh, smAl, smB);
  } else if (bid < 192) {     // K: 16x4 tiles
    int b2 = bid - 128;
    int m0 = (b2 >> 2) * 128, n0 = (b2 & 3) * 128;
    proj_tile<true, true>(k, WTs + (size_t)DM * DM, Khi, Klo, m0, n0,
                          smAh, smAl, smB);
  } else {                    // V: 16x4 tiles (plain, unswizzled out)
    int b2 = bid - 192;
    int m0 = (b2 >> 2) * 128, n0 = (b2 & 3) * 128;
    proj_tile<false, false>(v, WTs + (size_t)2 * DM * DM, Vb, nullptr, m0, n0,
                            smAh, smAl, smB);
  }
}

// ---------- output projection: 64x128 tiles, 256 blocks, 4 waves.
// A (AO, pre-swizzled) and B (WTs mat3) both via global_load_lds, dbuf,
// one barrier per k-step.
__global__ __launch_bounds__(256) void outproj_kernel(
    const bf16* __restrict__ AO, const bf16* __restrict__ Bo,
    float* __restrict__ out) {
  __shared__ bf16 smA[2 * 64 * 64];
  __shared__ bf16 smB[2 * 128 * 64];
  const int bid = ((blockIdx.x & 7) << 5) | (blockIdx.x >> 3);  // XCD-chunked
  const int m0 = (bid >> 2) * 64, n0 = (bid & 3) * 128;
  const int t = threadIdx.x;
  const int lane = t & 63;
  const int w = t >> 6;            // 0..3
  const int ln = lane & 15, hi4 = lane >> 4;
  const int rS = t >> 3, uS = t & 7;
  const f32x4 zf = {0.f, 0.f, 0.f, 0.f};
  f32x4 acc[4][2];
#pragma unroll
  for (int a = 0; a < 4; ++a)
#pragma unroll
    for (int b = 0; b < 2; ++b) acc[a][b] = zf;

  auto issueAB = [&](int ko, int buf) {
#pragma unroll
    for (int i = 0; i < 2; ++i) {
      const bf16* src = AO + (size_t)(m0 + i * 32 + rS) * 512 + ko + uS * 8;
      gl_lds16(src, smA + buf * 4096 + i * 2048 + w * 512);
    }
#pragma unroll
    for (int i = 0; i < 4; ++i) {
      const bf16* src = Bo + (size_t)(n0 + i * 32 + rS) * 512 + ko + uS * 8;
      gl_lds16(src, smB + buf * 8192 + i * 2048 + w * 512);
    }
  };

  issueAB(0, 0);
  __syncthreads();
  int buf = 0;
  for (int kt = 0; kt < 8; ++kt) {
    if (kt < 7) issueAB((kt + 1) * 64, buf ^ 1);
#pragma unroll
    for (int kk = 0; kk < 64; kk += 32) {
      const int ub = kk >> 3;
      bf16x8 af[4], bh[2];
#pragma unroll
      for (int mf = 0; mf < 4; ++mf)
        af[mf] = *(const bf16x8*)&smA[buf * 4096 + (mf * 16 + ln) * 64 +
                                      (((ub + hi4) ^ (ln & 7)) * 8)];
#pragma unroll
      for (int nf = 0; nf < 2; ++nf)
        bh[nf] = *(const bf16x8*)&smB[buf * 8192 + (w * 32 + nf * 16 + ln) * 64 +
                                      (((ub + hi4) ^ (ln & 7)) * 8)];
#pragma unroll
      for (int mf = 0; mf < 4; ++mf)
#pragma unroll
        for (int nf = 0; nf < 2; ++nf)
          acc[mf][nf] = mfma_bf16(af[mf], bh[nf], acc[mf][nf]);
    }
    __syncthreads();
    buf ^= 1;
  }
#pragma unroll
  for (int mf = 0; mf < 4; ++mf)
#pragma unroll
    for (int nf = 0; nf < 2; ++nf)
#pragma unroll
      for (int e = 0; e < 4; ++e)
        out[(size_t)(m0 + mf * 16 + hi4 * 4 + e) * 512 +
            n0 + w * 32 + nf * 16 + ln] = acc[mf][nf][e];
}

// ---------- banded attention: one (b,h,128-query tile) per block, 512 thr.
// Q/K staged via global_load_lds from pre-swizzled buffers; V reg-transposed.
__global__ __launch_bounds__(512, 2) void attn_kernel(
    const bf16* __restrict__ Qhi, const bf16* __restrict__ Qlo,
    const bf16* __restrict__ Khi, const bf16* __restrict__ Klo,
    const bf16* __restrict__ Vb, bf16* __restrict__ AO) {
  __shared__ bf16 smQh[128 * 64];
  __shared__ bf16 smQl[128 * 64];
  __shared__ bf16 smKh[128 * 64];
  __shared__ bf16 smKl[128 * 64];
  __shared__ bf16 smVt[64 * 128];   // [d][p], swizzled
  __shared__ bf16 smP[128 * 128];   // swizzled
  const int bid = ((blockIdx.x & 7) << 5) | (blockIdx.x >> 3);  // XCD-chunked
  const int qt = bid & 15;
  const int h  = (bid >> 4) & 7;
  const int b  = bid >> 7;
  const int j0 = qt * 128;
  const int pbase = (j0 >> 1) - 63;  // KV rows pbase..pbase+127; pbase%8 == 1
  const int t = threadIdx.x;
  const int lane = t & 63, w = t >> 6;   // 8 waves, 16 q-rows each
  const int ln = lane & 15, hi4 = lane >> 4;
  const int rS = t >> 3, uS = t & 7;

  // stage Q,K via gl_lds (pre-swizzled); V via regs into transposed smVt
#pragma unroll
  for (int i = 0; i < 2; ++i) {
    int r = i * 64 + rS;
    size_t qoff = ((size_t)(b * LQn + j0 + r)) * 512 + h * 64 + uS * 8;
    gl_lds16(Qhi + qoff, smQh + i * 4096 + w * 512);
    gl_lds16(Qlo + qoff, smQl + i * 4096 + w * 512);
    int p = pbase + r;
    p = p < 0 ? 0 : (p > LKVn - 1 ? LKVn - 1 : p);  // clamped rows masked later
    size_t koff = ((size_t)(b * LKVn + p)) * 512 + h * 64 + uS * 8;
    gl_lds16(Khi + koff, smKh + i * 4096 + w * 512);
    gl_lds16(Klo + koff, smKl + i * 4096 + w * 512);
    bf16x8 vv = *(const bf16x8*)(Vb + koff);
#pragma unroll
    for (int e = 0; e < 8; ++e) {
      int rv = uS * 8 + e;           // d-row of smVt
      smVt[rv * 128 + (((r >> 3) ^ (rv & 15)) * 8) + (r & 7)] = vv[e];
    }
  }
  __syncthreads();

  // S = Q K^T  (this wave: q-rows w*16..w*16+15, all 128 kv cols), 3-term.
  // K LDS rows hold global row p = pbase + r  ->  stored unit = u ^ (p&7),
  // and (p&7) == (r+1)&7 since pbase % 8 == 1.
  const f32x4 zf = {0.f, 0.f, 0.f, 0.f};
  f32x4 s[8];
#pragma unroll
  for (int cf = 0; cf < 8; ++cf) s[cf] = zf;
#pragma unroll
  for (int kk = 0; kk < 64; kk += 32) {
    const int ub = kk >> 3;
    int addrq = (w * 16 + ln) * 64 + (((ub + hi4) ^ (ln & 7)) * 8);
    bf16x8 ah = *(const bf16x8*)&smQh[addrq];
    bf16x8 al = *(const bf16x8*)&smQl[addrq];
#pragma unroll
    for (int cf = 0; cf < 8; ++cf) {
      int addrk = (cf * 16 + ln) * 64 + (((ub + hi4) ^ ((ln + 1) & 7)) * 8);
      bf16x8 bh = *(const bf16x8*)&smKh[addrk];
      bf16x8 bl = *(const bf16x8*)&smKl[addrk];
      s[cf] = mfma_bf16(ah, bh, s[cf]);
      s[cf] = mfma_bf16(ah, bl, s[cf]);
      s[cf] = mfma_bf16(al, bh, s[cf]);
    }
  }

  // mask + wave-parallel softmax, P -> bf16 LDS (swizzled)
#pragma unroll
  for (int r = 0; r < 4; ++r) {
    int rloc = w * 16 + hi4 * 4 + r;
    int wlo = rloc >> 1;
    int colmin = wlo > -pbase ? wlo : -pbase;
    int colmax = wlo + 63;
    float sv[8];
    float mx = -1e30f;
#pragma unroll
    for (int cf = 0; cf < 8; ++cf) {
      int col = cf * 16 + ln;
      float val = s[cf][r];
      bool ok = (col >= colmin) && (col <= colmax);
      sv[cf] = ok ? val : -1e30f;
      mx = fmaxf(mx, sv[cf]);
    }
#pragma unroll
    for (int msk = 1; msk < 16; msk <<= 1) mx = fmaxf(mx, __shfl_xor(mx, msk, 64));
    float sum = 0.f;
#pragma unroll
    for (int cf = 0; cf < 8; ++cf) {
      sv[cf] = __expf(sv[cf] - mx);
      sum += sv[cf];
    }
#pragma unroll
    for (int msk = 1; msk < 16; msk <<= 1) sum += __shfl_xor(sum, msk, 64);
    float rs = 1.0f / sum;
#pragma unroll
    for (int cf = 0; cf < 8; ++cf) {
      int uu = cf * 2 + (ln >> 3);
      smP[rloc * 128 + ((uu ^ (rloc & 15)) * 8) + (ln & 7)] = (bf16)(sv[cf] * rs);
    }
  }
  __syncthreads();

  // O = P @ V   (wave's 16 q-rows x 64 d)
  f32x4 o[4];
#pragma unroll
  for (int nf = 0; nf < 4; ++nf) o[nf] = zf;
#pragma unroll
  for (int kk = 0; kk < 128; kk += 32) {
    const int ub = kk >> 3;
    bf16x8 pa = *(const bf16x8*)&smP[(w * 16 + ln) * 128 + (((ub + hi4) ^ ln) * 8)];
#pragma unroll
    for (int nf = 0; nf < 4; ++nf) {
      int d = nf * 16 + ln;
      bf16x8 vf = *(const bf16x8*)&smVt[d * 128 + (((ub + hi4) ^ ln) * 8)];
      o[nf] = mfma_bf16(pa, vf, o[nf]);
    }
  }

  // write AO[b, j0+rloc, swizzled col] (pre-swizzled for outproj's gl_lds)
#pragma unroll
  for (int nf = 0; nf < 4; ++nf)
#pragma unroll
    for (int e = 0; e < 4; ++e) {
      int rloc = w * 16 + hi4 * 4 + e;
      int u3 = nf * 2 + (ln >> 3);
      int col = h * 64 + ((u3 ^ (rloc & 7)) << 3) + (ln & 7);
      AO[((size_t)(b * LQn + j0 + rloc)) * 512 + col] = (bf16)o[nf][e];
    }
}

extern "C" void kernel_launch(void* const* d_in, const int* in_sizes, int n_in,
                              void* d_out, int out_size, void* d_ws, size_t ws_size,
                              hipStream_t stream) {
  const float* q    = (const float*)d_in[0];
  const float* k    = (const float*)d_in[1];
  const float* v    = (const float*)d_in[2];
  const float* Wq   = (const float*)d_in[3];
  const float* Wk   = (const float*)d_in[4];
  const float* Wv   = (const float*)d_in[5];
  const float* Wout = (const float*)d_in[6];
  float* out = (float*)d_out;

  char* ws = (char*)d_ws;
  bf16* WTs  = (bf16*)ws;                          // 4*512*512*2 = 2 MB
  bf16* Qhi  = (bf16*)(ws + (size_t)(2  << 20));   // 4 MB
  bf16* Qlo  = (bf16*)(ws + (size_t)(6  << 20));   // 4 MB
  bf16* Khi  = (bf16*)(ws + (size_t)(10 << 20));   // 2 MB
  bf16* Klo  = (bf16*)(ws + (size_t)(12 << 20));   // 2 MB
  bf16* Vbuf = (bf16*)(ws + (size_t)(14 << 20));   // 2 MB
  bf16* AO   = (bf16*)(ws + (size_t)(16 << 20));   // 4 MB  (total 20 MB)

  transpose_w_kernel<<<256, 256, 0, stream>>>(Wq, Wk, Wv, Wout, WTs);
  proj_kernel<<<256, 512, 0, stream>>>(q, k, v, WTs, Qhi, Qlo, Khi, Klo, Vbuf);
  attn_kernel<<<256, 512, 0, stream>>>(Qhi, Qlo, Khi, Klo, Vbuf, AO);
  outproj_kernel<<<256, 256, 0, stream>>>(AO, WTs + (size_t)3 * DM * DM, out);
}